// Round 5
// baseline (491.161 us; speedup 1.0000x reference)
//
#include <hip/hip_runtime.h>
#include <hip/hip_bf16.h>
#include <math.h>

#define BB 32768
#define EE 16
#define HH 128
#define KP 160          // padded K: 16 x + 128 h + 16 zeros
#define XS 168          // xh row stride (bf16 elems): 168*2B=336B -> 16B-aligned
#define OBS 8
#define NSTEP 19
#define TPB 1024
#define MROWS 128       // batch rows per block: grid = 256 = 1 block/CU, SINGLE pass
#define KT 5            // K-tiles of 32

typedef short s16x8 __attribute__((ext_vector_type(8)));   // 8 bf16 (4 VGPRs), MFMA A/B frag
typedef float f32x4 __attribute__((ext_vector_type(4)));   // MFMA C/D frag

__device__ __forceinline__ float sigm(float x){ return __builtin_amdgcn_rcpf(1.0f + __expf(-x)); }
__device__ __forceinline__ float ftanh(float x){ float e = __expf(-2.f*x); return (1.f-e)*__builtin_amdgcn_rcpf(1.f+e); }
// NOTE: keep EXACTLY __float2bfloat16 (R2/R4 tripwire: any deviation in the realization
// moved absmax past threshold).
__device__ __forceinline__ unsigned short f2b(float x){
    __hip_bfloat16 h = __float2bfloat16(x);
    return *reinterpret_cast<unsigned short*>(&h);
}
__device__ __forceinline__ float b2f_(unsigned short u){ return __uint_as_float(((unsigned int)u) << 16); }

// Pack W_cat = [W_ih | W_hh] (K=144, zero-pad to 160) into MFMA A-operand fragment order,
// split into bf16 hi + lo.  Frag (JT 0..31, kt 0..4): lane l, elem j holds
//   W_cat[k = kt*32 + (l>>4)*8 + j][jg = JT*16 + (l&15)],  jg = 4*j_hidden + gate.
__global__ __launch_bounds__(256) void k_prep(
    const float* __restrict__ W_ih, const float* __restrict__ W_hh,
    unsigned short* __restrict__ Whi, unsigned short* __restrict__ Wlo)
{
    int idx = blockIdx.x * 256 + threadIdx.x;      // exactly 32*5*64*8 = 81920 threads
    int j    = idx & 7;
    int lane = (idx >> 3) & 63;
    int kt   = (idx >> 9) % KT;
    int JT   = idx / (KT * 512);
    int k  = kt * 32 + ((lane >> 4) << 3) + j;
    int jg = JT * 16 + (lane & 15);
    int col = (jg & 3) * HH + (jg >> 2);           // original gate row: g*128 + j_hidden
    float wv = 0.f;
    if (k < EE)            wv = W_ih[col * EE + k];
    else if (k < EE + HH)  wv = W_hh[col * HH + (k - EE)];
    unsigned short hi = f2b(wv);
    Whi[idx] = hi;
    Wlo[idx] = f2b(wv - b2f_(hi));
}

// Single-pass version: 256 blocks x 128 rows (was 512 x 64 = two sequential passes/CU).
// Per-output-element fp op order is IDENTICAL to the 335us baseline (same per-acc MFMA
// sequence, same cell, same 16-partial readout per row) -> bitwise-identical output.
// Wins: barrier count 114 -> 57, step-loop/addressing overhead amortized over 2x work,
// A-fragment refetch halved.  ~80 live VGPRs < 128 budget; LDS 87KB < 160KB @ 1 block/CU.
// waves_per_eu stays (4,4): (8,8)+s_sleep correlated with numeric failures (R2/R4) --
// do not reintroduce.
__global__ __attribute__((amdgpu_flat_work_group_size(TPB, TPB)))
           __attribute__((amdgpu_waves_per_eu(4, 4)))
void k_lstm(
    const float* __restrict__ obs,
    const float* __restrict__ W_emb, const float* __restrict__ b_emb,
    const float* __restrict__ b_ih,  const float* __restrict__ b_hh,
    const unsigned short* __restrict__ Whi, const unsigned short* __restrict__ Wlo,
    const float* __restrict__ W_out, const float* __restrict__ b_out,
    float* __restrict__ out)
{
    __shared__ unsigned short xhh[MROWS * XS];   // bf16 hi of [x(16)|h(128)|0(16)|pad]
    __shared__ unsigned short xhl[MROWS * XS];   // bf16 lo
    __shared__ float wout[2 * HH];
    __shared__ float wemb[EE * 2];
    __shared__ float bemb[EE];

    const int t    = threadIdx.x;
    const int lane = t & 63;
    const int w    = t >> 6;                     // wave 0..15: gate-cols jg in [w*32,(w+1)*32)
    const int row0 = blockIdx.x * MROWS;

    if (t < 2 * HH) wout[t] = W_out[t];          // rows 0,1 of W_out (contiguous)
    if (t < EE * 2) wemb[t] = W_emb[t];
    if (t < EE)     bemb[t] = b_emb[t];
    for (int i = t; i < MROWS * XS; i += TPB) { xhh[i] = 0; xhl[i] = 0; }

    // per-lane gate biases: acc[mt] reg r <-> jg = (2w+mt)*16 + (lane>>4)*4 + r
    f32x4 bias[2];
#pragma unroll
    for (int mt = 0; mt < 2; mt++)
#pragma unroll
        for (int r = 0; r < 4; r++) {
            int jg  = (2 * w + mt) * 16 + ((lane >> 4) << 2) + r;
            int col = (jg & 3) * HH + (jg >> 2);
            bias[mt][r] = b_ih[col] + b_hh[col];
        }
    const float bo0 = b_out[0], bo1 = b_out[1];

    // readout/embed mapping: rp = t&15 (16-way partials / 16 embed dims);
    // thread handles rows rrow and rrow+64 (identical per-row code -> same realization)
    const int rrow = t >> 4;                     // 0..63
    const int rp   = t & 15;

    const unsigned short* aHi = Whi + ((size_t)(2 * w) * KT) * 512 + (lane << 3);
    const unsigned short* aLo = Wlo + ((size_t)(2 * w) * KT) * 512 + (lane << 3);

    float c8[2][8];
#pragma unroll
    for (int mt = 0; mt < 2; mt++)
#pragma unroll
        for (int nt = 0; nt < 8; nt++) c8[mt][nt] = 0.f;
    float pl0[2] = {0.f, 0.f}, pl1[2] = {0.f, 0.f};  // p_last per handled row

    __syncthreads();

    // initial embed x[0] from obs delta: thread (rrow, rp=e), rows rrow and rrow+64
#pragma unroll
    for (int rr = 0; rr < 2; rr++) {
        const int lrow = rrow + rr * 64;
        const int grow = row0 + lrow;
        float d0 = obs[(size_t)1 * BB * 2 + grow * 2 + 0] - obs[(size_t)0 * BB * 2 + grow * 2 + 0];
        float d1 = obs[(size_t)1 * BB * 2 + grow * 2 + 1] - obs[(size_t)0 * BB * 2 + grow * 2 + 1];
        float v = bemb[rp] + d0 * wemb[2 * rp] + d1 * wemb[2 * rp + 1];
        v = v > 0.f ? v : 0.f;
        unsigned short hi = f2b(v);
        xhh[lrow * XS + rp] = hi;
        xhl[lrow * XS + rp] = f2b(v - b2f_(hi));
    }
    __syncthreads();

#pragma unroll 1
    for (int s = 0; s < NSTEP; s++) {
        // ---- gates GEMM: D[jg][row] = sum_k Wcat[k][jg] * xh[row][k]  (3-term bf16 split) ----
        f32x4 acc[2][8];
#pragma unroll
        for (int mt = 0; mt < 2; mt++)
#pragma unroll
            for (int nt = 0; nt < 8; nt++) acc[mt][nt] = bias[mt];

#pragma unroll 1
        for (int kt = 0; kt < KT; kt++) {
            const int fo0 = (0 * KT + kt) << 9;
            const int fo1 = (1 * KT + kt) << 9;
            s16x8 ah0 = *(const s16x8*)(aHi + fo0);
            s16x8 ah1 = *(const s16x8*)(aHi + fo1);
            s16x8 al0 = *(const s16x8*)(aLo + fo0);
            s16x8 al1 = *(const s16x8*)(aLo + fo1);
            const int koff = (kt << 5) + ((lane >> 4) << 3);
            const unsigned short* bhp = &xhh[(lane & 15) * XS + koff];
            const unsigned short* blp = &xhl[(lane & 15) * XS + koff];
#pragma unroll
            for (int nt = 0; nt < 8; nt++) {
                s16x8 bH = *(const s16x8*)(bhp + nt * 16 * XS);
                acc[0][nt] = __builtin_amdgcn_mfma_f32_16x16x32_bf16(ah0, bH, acc[0][nt], 0, 0, 0);
                acc[1][nt] = __builtin_amdgcn_mfma_f32_16x16x32_bf16(ah1, bH, acc[1][nt], 0, 0, 0);
                acc[0][nt] = __builtin_amdgcn_mfma_f32_16x16x32_bf16(al0, bH, acc[0][nt], 0, 0, 0);
                acc[1][nt] = __builtin_amdgcn_mfma_f32_16x16x32_bf16(al1, bH, acc[1][nt], 0, 0, 0);
            }
#pragma unroll
            for (int nt = 0; nt < 8; nt++) {
                s16x8 bL = *(const s16x8*)(blp + nt * 16 * XS);
                acc[0][nt] = __builtin_amdgcn_mfma_f32_16x16x32_bf16(ah0, bL, acc[0][nt], 0, 0, 0);
                acc[1][nt] = __builtin_amdgcn_mfma_f32_16x16x32_bf16(ah1, bL, acc[1][nt], 0, 0, 0);
            }
        }

        // ---- cell update: lane's 4 acc regs = (i,f,g,o) of hidden j -- no shuffles ----
        float hnew[2][8];
#pragma unroll
        for (int mt = 0; mt < 2; mt++)
#pragma unroll
            for (int nt = 0; nt < 8; nt++) {
                f32x4 g = acc[mt][nt];
                float cn = sigm(g[1]) * c8[mt][nt] + sigm(g[0]) * ftanh(g[2]);
                c8[mt][nt] = cn;
                hnew[mt][nt] = sigm(g[3]) * ftanh(cn);
            }

        __syncthreads();   // B_A: all waves finished reading xh for this step

#pragma unroll
        for (int mt = 0; mt < 2; mt++)
#pragma unroll
            for (int nt = 0; nt < 8; nt++) {
                int row = nt * 16 + (lane & 15);
                int j   = 8 * w + mt * 4 + (lane >> 4);
                float h = hnew[mt][nt];
                unsigned short hi = f2b(h);
                xhh[row * XS + EE + j] = hi;
                xhl[row * XS + EE + j] = f2b(h - b2f_(hi));
            }

        __syncthreads();   // B_B: new h visible to all

        // ---- readout + position + next-step embed: rows rrow and rrow+64 ----
#pragma unroll
        for (int rr = 0; rr < 2; rr++) {
            const int lrow = rrow + rr * 64;
            const int grow = row0 + lrow;
            const unsigned short* ph = &xhh[lrow * XS + EE + (rp << 3)];
            const unsigned short* pq = &xhl[lrow * XS + EE + (rp << 3)];
            s16x8 uh = *(const s16x8*)ph;
            s16x8 ul = *(const s16x8*)pq;
            float4 w0a = *(const float4*)&wout[(rp << 3)];
            float4 w0b = *(const float4*)&wout[(rp << 3) + 4];
            float4 w1a = *(const float4*)&wout[HH + (rp << 3)];
            float4 w1b = *(const float4*)&wout[HH + (rp << 3) + 4];
            float hv[8];
#pragma unroll
            for (int q = 0; q < 8; q++)
                hv[q] = b2f_((unsigned short)uh[q]) + b2f_((unsigned short)ul[q]);
            float r0 = hv[0]*w0a.x + hv[1]*w0a.y + hv[2]*w0a.z + hv[3]*w0a.w
                     + hv[4]*w0b.x + hv[5]*w0b.y + hv[6]*w0b.z + hv[7]*w0b.w;
            float r1 = hv[0]*w1a.x + hv[1]*w1a.y + hv[2]*w1a.z + hv[3]*w1a.w
                     + hv[4]*w1b.x + hv[5]*w1b.y + hv[6]*w1b.z + hv[7]*w1b.w;
#pragma unroll
            for (int m = 1; m < 16; m <<= 1) {
                r0 += __shfl_xor(r0, m, 64);
                r1 += __shfl_xor(r1, m, 64);
            }
            float base0, base1;
            if (s < OBS) {
                base0 = obs[(size_t)(s + 1) * BB * 2 + grow * 2 + 0];
                base1 = obs[(size_t)(s + 1) * BB * 2 + grow * 2 + 1];
            } else {
                base0 = pl0[rr]; base1 = pl1[rr];
            }
            float pos0 = base0 + r0 + bo0;
            float pos1 = base1 + r1 + bo1;
            if (rp == 0) {
                out[((size_t)s * BB + grow) * 2 + 0] = pos0;
                out[((size_t)s * BB + grow) * 2 + 1] = pos1;
            }
            if (s + 1 < NSTEP) {
                float d0, d1;
                if (s + 1 < OBS) {
                    d0 = obs[(size_t)(s + 2) * BB * 2 + grow * 2 + 0] - obs[(size_t)(s + 1) * BB * 2 + grow * 2 + 0];
                    d1 = obs[(size_t)(s + 2) * BB * 2 + grow * 2 + 1] - obs[(size_t)(s + 1) * BB * 2 + grow * 2 + 1];
                } else {
                    d0 = pos0 - pl0[rr];        // p_last_new - p_prev_new
                    d1 = pos1 - pl1[rr];
                }
                float v = bemb[rp] + d0 * wemb[2 * rp] + d1 * wemb[2 * rp + 1];
                v = v > 0.f ? v : 0.f;
                unsigned short hi = f2b(v);
                xhh[lrow * XS + rp] = hi;       // x-region write; disjoint from h-reads above
                xhl[lrow * XS + rp] = f2b(v - b2f_(hi));
            }
            pl0[rr] = pos0; pl1[rr] = pos1;
        }
        __syncthreads();   // B_C: x[s+1] + p_last consistent before next GEMM
    }
}

extern "C" void kernel_launch(void* const* d_in, const int* in_sizes, int n_in,
                              void* d_out, int out_size, void* d_ws, size_t ws_size,
                              hipStream_t stream)
{
    const float* obs   = (const float*)d_in[0];
    const float* W_emb = (const float*)d_in[1];
    const float* b_emb = (const float*)d_in[2];
    const float* W_ih  = (const float*)d_in[3];
    const float* b_ih  = (const float*)d_in[4];
    const float* W_hh  = (const float*)d_in[5];
    const float* b_hh  = (const float*)d_in[6];
    const float* W_out = (const float*)d_in[7];
    const float* b_out = (const float*)d_in[8];
    float* out = (float*)d_out;

    unsigned short* Whi = (unsigned short*)d_ws;        // 32*5*64*8 = 81920 bf16
    unsigned short* Wlo = Whi + 32 * KT * 64 * 8;       // another 81920

    hipLaunchKernelGGL(k_prep, dim3(32 * KT * 64 * 8 / 256), dim3(256), 0, stream,
                       W_ih, W_hh, Whi, Wlo);

    hipLaunchKernelGGL(k_lstm, dim3(BB / MROWS), dim3(TPB), 0, stream,
                       obs, W_emb, b_emb, b_ih, b_hh, Whi, Wlo, W_out, b_out, out);
}

// Round 7
// 360.038 us; speedup vs baseline: 1.3642x; 1.3642x over previous
//
#include <hip/hip_runtime.h>
#include <hip/hip_bf16.h>
#include <math.h>

#define BB 32768
#define EE 16
#define HH 128
#define KP 160          // padded K: 16 x + 128 h + 16 zeros
#define XS 168          // xh row stride (bf16 elems): 168*2B=336B -> bank-spread, 16B-aligned
#define OBS 8
#define NSTEP 19
#define TPB 1024
#define MROWS 64        // batch rows per block
#define KT 5            // K-tiles of 32

typedef short s16x8 __attribute__((ext_vector_type(8)));   // 8 bf16 (4 VGPRs), MFMA A/B frag
typedef float f32x4 __attribute__((ext_vector_type(4)));   // MFMA C/D frag

__device__ __forceinline__ float sigm(float x){ return __builtin_amdgcn_rcpf(1.0f + __expf(-x)); }
__device__ __forceinline__ float ftanh(float x){ float e = __expf(-2.f*x); return (1.f-e)*__builtin_amdgcn_rcpf(1.f+e); }
// NOTE: keep EXACTLY __float2bfloat16 (R2 tripwire).
__device__ __forceinline__ unsigned short f2b(float x){
    __hip_bfloat16 h = __float2bfloat16(x);
    return *reinterpret_cast<unsigned short*>(&h);
}
__device__ __forceinline__ float b2f_(unsigned short u){ return __uint_as_float(((unsigned int)u) << 16); }

// Pack W_cat = [W_ih | W_hh] (K=144, zero-pad to 160) into MFMA A-operand fragment order,
// split into bf16 hi + lo.  Frag (JT 0..31, kt 0..4): lane l, elem j holds
//   W_cat[k = kt*32 + (l>>4)*8 + j][jg = JT*16 + (l&15)],  jg = 4*j_hidden + gate.
__global__ __launch_bounds__(256) void k_prep(
    const float* __restrict__ W_ih, const float* __restrict__ W_hh,
    unsigned short* __restrict__ Whi, unsigned short* __restrict__ Wlo)
{
    int idx = blockIdx.x * 256 + threadIdx.x;      // exactly 32*5*64*8 = 81920 threads
    int j    = idx & 7;
    int lane = (idx >> 3) & 63;
    int kt   = (idx >> 9) % KT;
    int JT   = idx / (KT * 512);
    int k  = kt * 32 + ((lane >> 4) << 3) + j;
    int jg = JT * 16 + (lane & 15);
    int col = (jg & 3) * HH + (jg >> 2);           // original gate row: g*128 + j_hidden
    float wv = 0.f;
    if (k < EE)            wv = W_ih[col * EE + k];
    else if (k < EE + HH)  wv = W_hh[col * HH + (k - EE)];
    unsigned short hi = f2b(wv);
    Whi[idx] = hi;
    Wlo[idx] = f2b(wv - b2f_(hi));
}

// Occupancy: waves_per_eu(4,8).  min=4 keeps the codegen register budget at 128 VGPRs
// (identical codegen to the 335us baseline, which allocated 56 -- R5 showed min=4 is the
// floor for a 16-wave block, and R2/R4 showed min=8's 64-reg budget corrupts numerics via
// spill-restructured codegen).  max=8 lets the HARDWARE co-schedule two 16-wave blocks
// per CU (56 VGPR <= 64, LDS 2x44.5KB < 160KB), so block A's barrier-lockstep GEMM (MFMA
// pipe) overlaps block B's cell/readout (VALU pipe).  No other change vs baseline.
__global__ __attribute__((amdgpu_flat_work_group_size(TPB, TPB)))
           __attribute__((amdgpu_waves_per_eu(4, 8)))
void k_lstm(
    const float* __restrict__ obs,
    const float* __restrict__ W_emb, const float* __restrict__ b_emb,
    const float* __restrict__ b_ih,  const float* __restrict__ b_hh,
    const unsigned short* __restrict__ Whi, const unsigned short* __restrict__ Wlo,
    const float* __restrict__ W_out, const float* __restrict__ b_out,
    float* __restrict__ out)
{
    __shared__ unsigned short xhh[MROWS * XS];   // bf16 hi of [x(16)|h(128)|0(16)|pad]
    __shared__ unsigned short xhl[MROWS * XS];   // bf16 lo
    __shared__ float wout[2 * HH];
    __shared__ float wemb[EE * 2];
    __shared__ float bemb[EE];

    const int t    = threadIdx.x;
    const int lane = t & 63;
    const int w    = t >> 6;                     // wave 0..15: gate-cols jg in [w*32,(w+1)*32)
    const int row0 = blockIdx.x * MROWS;

    if (t < 2 * HH) wout[t] = W_out[t];          // rows 0,1 of W_out (contiguous)
    if (t < EE * 2) wemb[t] = W_emb[t];
    if (t < EE)     bemb[t] = b_emb[t];
    for (int i = t; i < MROWS * XS; i += TPB) { xhh[i] = 0; xhl[i] = 0; }

    // per-lane gate biases: acc[mt] reg r <-> jg = (2w+mt)*16 + (lane>>4)*4 + r
    f32x4 bias[2];
#pragma unroll
    for (int mt = 0; mt < 2; mt++)
#pragma unroll
        for (int r = 0; r < 4; r++) {
            int jg  = (2 * w + mt) * 16 + ((lane >> 4) << 2) + r;
            int col = (jg & 3) * HH + (jg >> 2);
            bias[mt][r] = b_ih[col] + b_hh[col];
        }
    const float bo0 = b_out[0], bo1 = b_out[1];

    // readout/embed mapping: row = t>>4 (64 rows), rp = t&15 (16-way partials / 16 embed dims)
    const int rrow = t >> 4;
    const int rp   = t & 15;
    const int grow = row0 + rrow;

    const unsigned short* aHi = Whi + ((size_t)(2 * w) * KT) * 512 + (lane << 3);
    const unsigned short* aLo = Wlo + ((size_t)(2 * w) * KT) * 512 + (lane << 3);

    float c8[2][4];
#pragma unroll
    for (int mt = 0; mt < 2; mt++)
#pragma unroll
        for (int nt = 0; nt < 4; nt++) c8[mt][nt] = 0.f;
    float pl0 = 0.f, pl1 = 0.f;                  // p_last (per-row, maintained by all 16 rp-threads)

    __syncthreads();

    // initial embed x[0] from obs delta: thread (rrow, rp=e)
    {
        float d0 = obs[(size_t)1 * BB * 2 + grow * 2 + 0] - obs[(size_t)0 * BB * 2 + grow * 2 + 0];
        float d1 = obs[(size_t)1 * BB * 2 + grow * 2 + 1] - obs[(size_t)0 * BB * 2 + grow * 2 + 1];
        float v = bemb[rp] + d0 * wemb[2 * rp] + d1 * wemb[2 * rp + 1];
        v = v > 0.f ? v : 0.f;
        unsigned short hi = f2b(v);
        xhh[rrow * XS + rp] = hi;
        xhl[rrow * XS + rp] = f2b(v - b2f_(hi));
    }
    __syncthreads();

#pragma unroll 1
    for (int s = 0; s < NSTEP; s++) {
        // ---- gates GEMM: D[jg][row] = sum_k Wcat[k][jg] * xh[row][k]  (3-term bf16 split) ----
        f32x4 acc[2][4];
#pragma unroll
        for (int mt = 0; mt < 2; mt++)
#pragma unroll
            for (int nt = 0; nt < 4; nt++) acc[mt][nt] = bias[mt];

#pragma unroll 1
        for (int kt = 0; kt < KT; kt++) {
            const int fo0 = (0 * KT + kt) << 9;
            const int fo1 = (1 * KT + kt) << 9;
            s16x8 ah0 = *(const s16x8*)(aHi + fo0);
            s16x8 ah1 = *(const s16x8*)(aHi + fo1);
            s16x8 al0 = *(const s16x8*)(aLo + fo0);
            s16x8 al1 = *(const s16x8*)(aLo + fo1);
            const int koff = (kt << 5) + ((lane >> 4) << 3);
            const unsigned short* bhp = &xhh[(lane & 15) * XS + koff];
            const unsigned short* blp = &xhl[(lane & 15) * XS + koff];
#pragma unroll
            for (int nt = 0; nt < 4; nt++) {
                s16x8 bH = *(const s16x8*)(bhp + nt * 16 * XS);
                acc[0][nt] = __builtin_amdgcn_mfma_f32_16x16x32_bf16(ah0, bH, acc[0][nt], 0, 0, 0);
                acc[1][nt] = __builtin_amdgcn_mfma_f32_16x16x32_bf16(ah1, bH, acc[1][nt], 0, 0, 0);
                acc[0][nt] = __builtin_amdgcn_mfma_f32_16x16x32_bf16(al0, bH, acc[0][nt], 0, 0, 0);
                acc[1][nt] = __builtin_amdgcn_mfma_f32_16x16x32_bf16(al1, bH, acc[1][nt], 0, 0, 0);
            }
#pragma unroll
            for (int nt = 0; nt < 4; nt++) {
                s16x8 bL = *(const s16x8*)(blp + nt * 16 * XS);
                acc[0][nt] = __builtin_amdgcn_mfma_f32_16x16x32_bf16(ah0, bL, acc[0][nt], 0, 0, 0);
                acc[1][nt] = __builtin_amdgcn_mfma_f32_16x16x32_bf16(ah1, bL, acc[1][nt], 0, 0, 0);
            }
        }

        // ---- cell update: lane's 4 acc regs = (i,f,g,o) of hidden j -- no shuffles ----
        float hnew[2][4];
#pragma unroll
        for (int mt = 0; mt < 2; mt++)
#pragma unroll
            for (int nt = 0; nt < 4; nt++) {
                f32x4 g = acc[mt][nt];
                float cn = sigm(g[1]) * c8[mt][nt] + sigm(g[0]) * ftanh(g[2]);
                c8[mt][nt] = cn;
                hnew[mt][nt] = sigm(g[3]) * ftanh(cn);
            }

        __syncthreads();   // B_A: all waves finished reading xh for this step

#pragma unroll
        for (int mt = 0; mt < 2; mt++)
#pragma unroll
            for (int nt = 0; nt < 4; nt++) {
                int row = nt * 16 + (lane & 15);
                int j   = 8 * w + mt * 4 + (lane >> 4);
                float h = hnew[mt][nt];
                unsigned short hi = f2b(h);
                xhh[row * XS + EE + j] = hi;
                xhl[row * XS + EE + j] = f2b(h - b2f_(hi));
            }

        __syncthreads();   // B_B: new h visible to all

        // ---- readout + position + next-step embed ----
        {
            const unsigned short* ph = &xhh[rrow * XS + EE + (rp << 3)];
            const unsigned short* pq = &xhl[rrow * XS + EE + (rp << 3)];
            s16x8 uh = *(const s16x8*)ph;
            s16x8 ul = *(const s16x8*)pq;
            float4 w0a = *(const float4*)&wout[(rp << 3)];
            float4 w0b = *(const float4*)&wout[(rp << 3) + 4];
            float4 w1a = *(const float4*)&wout[HH + (rp << 3)];
            float4 w1b = *(const float4*)&wout[HH + (rp << 3) + 4];
            float hv[8];
#pragma unroll
            for (int q = 0; q < 8; q++)
                hv[q] = b2f_((unsigned short)uh[q]) + b2f_((unsigned short)ul[q]);
            float r0 = hv[0]*w0a.x + hv[1]*w0a.y + hv[2]*w0a.z + hv[3]*w0a.w
                     + hv[4]*w0b.x + hv[5]*w0b.y + hv[6]*w0b.z + hv[7]*w0b.w;
            float r1 = hv[0]*w1a.x + hv[1]*w1a.y + hv[2]*w1a.z + hv[3]*w1a.w
                     + hv[4]*w1b.x + hv[5]*w1b.y + hv[6]*w1b.z + hv[7]*w1b.w;
#pragma unroll
            for (int m = 1; m < 16; m <<= 1) {
                r0 += __shfl_xor(r0, m, 64);
                r1 += __shfl_xor(r1, m, 64);
            }
            float base0, base1;
            if (s < OBS) {
                base0 = obs[(size_t)(s + 1) * BB * 2 + grow * 2 + 0];
                base1 = obs[(size_t)(s + 1) * BB * 2 + grow * 2 + 1];
            } else {
                base0 = pl0; base1 = pl1;
            }
            float pos0 = base0 + r0 + bo0;
            float pos1 = base1 + r1 + bo1;
            if (rp == 0) {
                out[((size_t)s * BB + grow) * 2 + 0] = pos0;
                out[((size_t)s * BB + grow) * 2 + 1] = pos1;
            }
            if (s + 1 < NSTEP) {
                float d0, d1;
                if (s + 1 < OBS) {
                    d0 = obs[(size_t)(s + 2) * BB * 2 + grow * 2 + 0] - obs[(size_t)(s + 1) * BB * 2 + grow * 2 + 0];
                    d1 = obs[(size_t)(s + 2) * BB * 2 + grow * 2 + 1] - obs[(size_t)(s + 1) * BB * 2 + grow * 2 + 1];
                } else {
                    d0 = pos0 - pl0;            // p_last_new - p_prev_new
                    d1 = pos1 - pl1;
                }
                float v = bemb[rp] + d0 * wemb[2 * rp] + d1 * wemb[2 * rp + 1];
                v = v > 0.f ? v : 0.f;
                unsigned short hi = f2b(v);
                xhh[rrow * XS + rp] = hi;       // x-region write; disjoint from h-reads above
                xhl[rrow * XS + rp] = f2b(v - b2f_(hi));
            }
            pl0 = pos0; pl1 = pos1;
        }
        __syncthreads();   // B_C: x[s+1] + plpp consistent before next GEMM
    }
}

extern "C" void kernel_launch(void* const* d_in, const int* in_sizes, int n_in,
                              void* d_out, int out_size, void* d_ws, size_t ws_size,
                              hipStream_t stream)
{
    const float* obs   = (const float*)d_in[0];
    const float* W_emb = (const float*)d_in[1];
    const float* b_emb = (const float*)d_in[2];
    const float* W_ih  = (const float*)d_in[3];
    const float* b_ih  = (const float*)d_in[4];
    const float* W_hh  = (const float*)d_in[5];
    const float* b_hh  = (const float*)d_in[6];
    const float* W_out = (const float*)d_in[7];
    const float* b_out = (const float*)d_in[8];
    float* out = (float*)d_out;

    unsigned short* Whi = (unsigned short*)d_ws;        // 32*5*64*8 = 81920 bf16
    unsigned short* Wlo = Whi + 32 * KT * 64 * 8;       // another 81920

    hipLaunchKernelGGL(k_prep, dim3(32 * KT * 64 * 8 / 256), dim3(256), 0, stream,
                       W_ih, W_hh, Whi, Wlo);

    hipLaunchKernelGGL(k_lstm, dim3(BB / MROWS), dim3(TPB), 0, stream,
                       obs, W_emb, b_emb, b_ih, b_hh, Whi, Wlo, W_out, b_out, out);
}

// Round 9
// 262.126 us; speedup vs baseline: 1.8738x; 1.3735x over previous
//
#include <hip/hip_runtime.h>
#include <hip/hip_bf16.h>
#include <math.h>

#define BB 32768
#define EE 16
#define HH 128
#define KP 160          // padded K: 16 x + 128 h + 16 zeros
#define XS 168          // xh row stride (bf16 elems): 168*2B=336B -> bank-spread, 16B-aligned
#define OBS 8
#define NSTEP 19
#define TPB 1024
#define MROWS 64        // batch rows per block
#define KT 5            // K-tiles of 32

typedef short s16x8 __attribute__((ext_vector_type(8)));   // 8 bf16 (4 VGPRs), MFMA A/B frag
typedef float f32x4 __attribute__((ext_vector_type(4)));   // MFMA C/D frag

__device__ __forceinline__ float sigm(float x){ return __builtin_amdgcn_rcpf(1.0f + __expf(-x)); }
__device__ __forceinline__ float ftanh(float x){ float e = __expf(-2.f*x); return (1.f-e)*__builtin_amdgcn_rcpf(1.f+e); }
// NOTE: keep EXACTLY __float2bfloat16 (R2 tripwire: its rounding is not the RNE bit-trick;
// swapping realizations moves absmax by ~8 ULP over the 19-step recurrence).
__device__ __forceinline__ unsigned short f2b(float x){
    __hip_bfloat16 h = __float2bfloat16(x);
    return *reinterpret_cast<unsigned short*>(&h);
}
__device__ __forceinline__ float b2f_(unsigned short u){ return __uint_as_float(((unsigned int)u) << 16); }

// Pack W_cat = [W_ih | W_hh] (K=144, zero-pad to 160) into MFMA A-operand fragment order,
// SINGLE bf16 (hi only -- the lo-term was dropped: contracting LSTM dynamics bound the
// single-term bf16 GEMM error at ~0.03 final vs threshold 0.127).  Frag (JT 0..31,
// kt 0..4): lane l, elem j holds W_cat[k = kt*32+(l>>4)*8+j][jg = JT*16+(l&15)].
__global__ __launch_bounds__(256) void k_prep(
    const float* __restrict__ W_ih, const float* __restrict__ W_hh,
    unsigned short* __restrict__ Whi)
{
    int idx = blockIdx.x * 256 + threadIdx.x;      // exactly 32*5*64*8 = 81920 threads
    int j    = idx & 7;
    int lane = (idx >> 3) & 63;
    int kt   = (idx >> 9) % KT;
    int JT   = idx / (KT * 512);
    int k  = kt * 32 + ((lane >> 4) << 3) + j;
    int jg = JT * 16 + (lane & 15);
    int col = (jg & 3) * HH + (jg >> 2);           // original gate row: g*128 + j_hidden
    float wv = 0.f;
    if (k < EE)            wv = W_ih[col * EE + k];
    else if (k < EE + HH)  wv = W_hh[col * HH + (k - EE)];
    Whi[idx] = f2b(wv);
}

// R7 structure (best passing: 360us, attrs (4,8)) minus the entire lo-term machinery:
// single bf16 xh buffer, 1 MFMA term per A-frag (40 MFMA/step/wave vs 120), 20 LDS
// B-reads/step vs 40, 8 h-write conversions vs 16.  All surviving code byte-identical
// to R7 (cell/readout/embed text unchanged).
__global__ __attribute__((amdgpu_flat_work_group_size(TPB, TPB)))
           __attribute__((amdgpu_waves_per_eu(4, 8)))
void k_lstm(
    const float* __restrict__ obs,
    const float* __restrict__ W_emb, const float* __restrict__ b_emb,
    const float* __restrict__ b_ih,  const float* __restrict__ b_hh,
    const unsigned short* __restrict__ Whi,
    const float* __restrict__ W_out, const float* __restrict__ b_out,
    float* __restrict__ out)
{
    __shared__ unsigned short xhh[MROWS * XS];   // bf16 of [x(16)|h(128)|0(16)|pad]
    __shared__ float wout[2 * HH];
    __shared__ float wemb[EE * 2];
    __shared__ float bemb[EE];

    const int t    = threadIdx.x;
    const int lane = t & 63;
    const int w    = t >> 6;                     // wave 0..15: gate-cols jg in [w*32,(w+1)*32)
    const int row0 = blockIdx.x * MROWS;

    if (t < 2 * HH) wout[t] = W_out[t];          // rows 0,1 of W_out (contiguous)
    if (t < EE * 2) wemb[t] = W_emb[t];
    if (t < EE)     bemb[t] = b_emb[t];
    for (int i = t; i < MROWS * XS; i += TPB) { xhh[i] = 0; }

    // per-lane gate biases: acc[mt] reg r <-> jg = (2w+mt)*16 + (lane>>4)*4 + r
    f32x4 bias[2];
#pragma unroll
    for (int mt = 0; mt < 2; mt++)
#pragma unroll
        for (int r = 0; r < 4; r++) {
            int jg  = (2 * w + mt) * 16 + ((lane >> 4) << 2) + r;
            int col = (jg & 3) * HH + (jg >> 2);
            bias[mt][r] = b_ih[col] + b_hh[col];
        }
    const float bo0 = b_out[0], bo1 = b_out[1];

    // readout/embed mapping: row = t>>4 (64 rows), rp = t&15 (16-way partials / 16 embed dims)
    const int rrow = t >> 4;
    const int rp   = t & 15;
    const int grow = row0 + rrow;

    const unsigned short* aHi = Whi + ((size_t)(2 * w) * KT) * 512 + (lane << 3);

    float c8[2][4];
#pragma unroll
    for (int mt = 0; mt < 2; mt++)
#pragma unroll
        for (int nt = 0; nt < 4; nt++) c8[mt][nt] = 0.f;
    float pl0 = 0.f, pl1 = 0.f;                  // p_last (per-row, maintained by all 16 rp-threads)

    __syncthreads();

    // initial embed x[0] from obs delta: thread (rrow, rp=e)
    {
        float d0 = obs[(size_t)1 * BB * 2 + grow * 2 + 0] - obs[(size_t)0 * BB * 2 + grow * 2 + 0];
        float d1 = obs[(size_t)1 * BB * 2 + grow * 2 + 1] - obs[(size_t)0 * BB * 2 + grow * 2 + 1];
        float v = bemb[rp] + d0 * wemb[2 * rp] + d1 * wemb[2 * rp + 1];
        v = v > 0.f ? v : 0.f;
        xhh[rrow * XS + rp] = f2b(v);
    }
    __syncthreads();

#pragma unroll 1
    for (int s = 0; s < NSTEP; s++) {
        // ---- gates GEMM: D[jg][row] = sum_k Wcat[k][jg] * xh[row][k]  (single-term bf16) ----
        f32x4 acc[2][4];
#pragma unroll
        for (int mt = 0; mt < 2; mt++)
#pragma unroll
            for (int nt = 0; nt < 4; nt++) acc[mt][nt] = bias[mt];

#pragma unroll 1
        for (int kt = 0; kt < KT; kt++) {
            const int fo0 = (0 * KT + kt) << 9;
            const int fo1 = (1 * KT + kt) << 9;
            s16x8 ah0 = *(const s16x8*)(aHi + fo0);
            s16x8 ah1 = *(const s16x8*)(aHi + fo1);
            const int koff = (kt << 5) + ((lane >> 4) << 3);
            const unsigned short* bhp = &xhh[(lane & 15) * XS + koff];
#pragma unroll
            for (int nt = 0; nt < 4; nt++) {
                s16x8 bH = *(const s16x8*)(bhp + nt * 16 * XS);
                acc[0][nt] = __builtin_amdgcn_mfma_f32_16x16x32_bf16(ah0, bH, acc[0][nt], 0, 0, 0);
                acc[1][nt] = __builtin_amdgcn_mfma_f32_16x16x32_bf16(ah1, bH, acc[1][nt], 0, 0, 0);
            }
        }

        // ---- cell update: lane's 4 acc regs = (i,f,g,o) of hidden j -- no shuffles ----
        float hnew[2][4];
#pragma unroll
        for (int mt = 0; mt < 2; mt++)
#pragma unroll
            for (int nt = 0; nt < 4; nt++) {
                f32x4 g = acc[mt][nt];
                float cn = sigm(g[1]) * c8[mt][nt] + sigm(g[0]) * ftanh(g[2]);
                c8[mt][nt] = cn;
                hnew[mt][nt] = sigm(g[3]) * ftanh(cn);
            }

        __syncthreads();   // B_A: all waves finished reading xh for this step

#pragma unroll
        for (int mt = 0; mt < 2; mt++)
#pragma unroll
            for (int nt = 0; nt < 4; nt++) {
                int row = nt * 16 + (lane & 15);
                int j   = 8 * w + mt * 4 + (lane >> 4);
                xhh[row * XS + EE + j] = f2b(hnew[mt][nt]);
            }

        __syncthreads();   // B_B: new h visible to all

        // ---- readout + position + next-step embed ----
        {
            const unsigned short* ph = &xhh[rrow * XS + EE + (rp << 3)];
            s16x8 uh = *(const s16x8*)ph;
            float4 w0a = *(const float4*)&wout[(rp << 3)];
            float4 w0b = *(const float4*)&wout[(rp << 3) + 4];
            float4 w1a = *(const float4*)&wout[HH + (rp << 3)];
            float4 w1b = *(const float4*)&wout[HH + (rp << 3) + 4];
            float hv[8];
#pragma unroll
            for (int q = 0; q < 8; q++)
                hv[q] = b2f_((unsigned short)uh[q]);
            float r0 = hv[0]*w0a.x + hv[1]*w0a.y + hv[2]*w0a.z + hv[3]*w0a.w
                     + hv[4]*w0b.x + hv[5]*w0b.y + hv[6]*w0b.z + hv[7]*w0b.w;
            float r1 = hv[0]*w1a.x + hv[1]*w1a.y + hv[2]*w1a.z + hv[3]*w1a.w
                     + hv[4]*w1b.x + hv[5]*w1b.y + hv[6]*w1b.z + hv[7]*w1b.w;
#pragma unroll
            for (int m = 1; m < 16; m <<= 1) {
                r0 += __shfl_xor(r0, m, 64);
                r1 += __shfl_xor(r1, m, 64);
            }
            float base0, base1;
            if (s < OBS) {
                base0 = obs[(size_t)(s + 1) * BB * 2 + grow * 2 + 0];
                base1 = obs[(size_t)(s + 1) * BB * 2 + grow * 2 + 1];
            } else {
                base0 = pl0; base1 = pl1;
            }
            float pos0 = base0 + r0 + bo0;
            float pos1 = base1 + r1 + bo1;
            if (rp == 0) {
                out[((size_t)s * BB + grow) * 2 + 0] = pos0;
                out[((size_t)s * BB + grow) * 2 + 1] = pos1;
            }
            if (s + 1 < NSTEP) {
                float d0, d1;
                if (s + 1 < OBS) {
                    d0 = obs[(size_t)(s + 2) * BB * 2 + grow * 2 + 0] - obs[(size_t)(s + 1) * BB * 2 + grow * 2 + 0];
                    d1 = obs[(size_t)(s + 2) * BB * 2 + grow * 2 + 1] - obs[(size_t)(s + 1) * BB * 2 + grow * 2 + 1];
                } else {
                    d0 = pos0 - pl0;            // p_last_new - p_prev_new
                    d1 = pos1 - pl1;
                }
                float v = bemb[rp] + d0 * wemb[2 * rp] + d1 * wemb[2 * rp + 1];
                v = v > 0.f ? v : 0.f;
                xhh[rrow * XS + rp] = f2b(v);   // x-region write; disjoint from h-reads above
            }
            pl0 = pos0; pl1 = pos1;
        }
        __syncthreads();   // B_C: x[s+1] + p_last consistent before next GEMM
    }
}

extern "C" void kernel_launch(void* const* d_in, const int* in_sizes, int n_in,
                              void* d_out, int out_size, void* d_ws, size_t ws_size,
                              hipStream_t stream)
{
    const float* obs   = (const float*)d_in[0];
    const float* W_emb = (const float*)d_in[1];
    const float* b_emb = (const float*)d_in[2];
    const float* W_ih  = (const float*)d_in[3];
    const float* b_ih  = (const float*)d_in[4];
    const float* W_hh  = (const float*)d_in[5];
    const float* b_hh  = (const float*)d_in[6];
    const float* W_out = (const float*)d_in[7];
    const float* b_out = (const float*)d_in[8];
    float* out = (float*)d_out;

    unsigned short* Whi = (unsigned short*)d_ws;        // 32*5*64*8 = 81920 bf16

    hipLaunchKernelGGL(k_prep, dim3(32 * KT * 64 * 8 / 256), dim3(256), 0, stream,
                       W_ih, W_hh, Whi);

    hipLaunchKernelGGL(k_lstm, dim3(BB / MROWS), dim3(TPB), 0, stream,
                       obs, W_emb, b_emb, b_ih, b_hh, Whi, W_out, b_out, out);
}

// Round 10
// 259.472 us; speedup vs baseline: 1.8929x; 1.0102x over previous
//
#include <hip/hip_runtime.h>
#include <hip/hip_fp16.h>
#include <math.h>

#define BB 32768
#define EE 16
#define HH 128
#define KP 160          // padded K: 16 x + 128 h + 16 zeros
#define XS 168          // xh row stride (f16 elems): 168*2B=336B -> bank-spread, 16B-aligned
#define OBS 8
#define NSTEP 19
#define TPB 1024
#define MROWS 64        // batch rows per block
#define KT 5            // K-tiles of 32

typedef short s16x8 __attribute__((ext_vector_type(8)));     // raw 16-bit x8 (LDS storage view)
typedef _Float16 h16x8 __attribute__((ext_vector_type(8)));  // 8 fp16 (4 VGPRs), MFMA A/B frag
typedef float f32x4 __attribute__((ext_vector_type(4)));     // MFMA C/D frag

__device__ __forceinline__ float sigm(float x){ return __builtin_amdgcn_rcpf(1.0f + __expf(-x)); }
__device__ __forceinline__ float ftanh(float x){ float e = __expf(-2.f*x); return (1.f-e)*__builtin_amdgcn_rcpf(1.f+e); }
// fp16 conversions: single HW op each (v_cvt_f16_f32 / v_cvt_f32_f16), vs the ~6-op
// software RNE of __float2bfloat16.  9 conversions/thread/step -> ~100 cyc/wave/step saved.
__device__ __forceinline__ unsigned short f2h(float x){
    __half h = __float2half(x);                 // RNE
    return __half_as_ushort(h);
}
__device__ __forceinline__ float h2f(unsigned short u){ return __half2float(__ushort_as_half(u)); }

// Pack W_cat = [W_ih | W_hh] (K=144, zero-pad to 160) into MFMA A-operand fragment order,
// single fp16 (11-bit mantissa: ~8x finer than bf16 -> gate error shrinks, absmax margin
// grows; range safe: |W| ~ 2.5 max).  Frag (JT 0..31, kt 0..4): lane l, elem j holds
//   W_cat[k = kt*32 + (l>>4)*8 + j][jg = JT*16 + (l&15)],  jg = 4*j_hidden + gate.
__global__ __launch_bounds__(256) void k_prep(
    const float* __restrict__ W_ih, const float* __restrict__ W_hh,
    unsigned short* __restrict__ Whi)
{
    int idx = blockIdx.x * 256 + threadIdx.x;      // exactly 32*5*64*8 = 81920 threads
    int j    = idx & 7;
    int lane = (idx >> 3) & 63;
    int kt   = (idx >> 9) % KT;
    int JT   = idx / (KT * 512);
    int k  = kt * 32 + ((lane >> 4) << 3) + j;
    int jg = JT * 16 + (lane & 15);
    int col = (jg & 3) * HH + (jg >> 2);           // original gate row: g*128 + j_hidden
    float wv = 0.f;
    if (k < EE)            wv = W_ih[col * EE + k];
    else if (k < EE + HH)  wv = W_hh[col * HH + (k - EE)];
    Whi[idx] = f2h(wv);
}

// R9 structure exactly (best passing: 262us), dtype swapped bf16 -> fp16 throughout the
// GEMM/state path: mfma_f32_16x16x32_f16 (same shape, same layout, same rate), HW cvt
// instead of software bf16 RNE, fp16 h/x quantization (8x finer).  fp32 cell/readout
// math, 3-barrier schedule, tiling, attrs all byte-identical to R9.
__global__ __attribute__((amdgpu_flat_work_group_size(TPB, TPB)))
           __attribute__((amdgpu_waves_per_eu(4, 8)))
void k_lstm(
    const float* __restrict__ obs,
    const float* __restrict__ W_emb, const float* __restrict__ b_emb,
    const float* __restrict__ b_ih,  const float* __restrict__ b_hh,
    const unsigned short* __restrict__ Whi,
    const float* __restrict__ W_out, const float* __restrict__ b_out,
    float* __restrict__ out)
{
    __shared__ unsigned short xhh[MROWS * XS];   // fp16 of [x(16)|h(128)|0(16)|pad]
    __shared__ float wout[2 * HH];
    __shared__ float wemb[EE * 2];
    __shared__ float bemb[EE];

    const int t    = threadIdx.x;
    const int lane = t & 63;
    const int w    = t >> 6;                     // wave 0..15: gate-cols jg in [w*32,(w+1)*32)
    const int row0 = blockIdx.x * MROWS;

    if (t < 2 * HH) wout[t] = W_out[t];          // rows 0,1 of W_out (contiguous)
    if (t < EE * 2) wemb[t] = W_emb[t];
    if (t < EE)     bemb[t] = b_emb[t];
    for (int i = t; i < MROWS * XS; i += TPB) { xhh[i] = 0; }

    // per-lane gate biases: acc[mt] reg r <-> jg = (2w+mt)*16 + (lane>>4)*4 + r
    f32x4 bias[2];
#pragma unroll
    for (int mt = 0; mt < 2; mt++)
#pragma unroll
        for (int r = 0; r < 4; r++) {
            int jg  = (2 * w + mt) * 16 + ((lane >> 4) << 2) + r;
            int col = (jg & 3) * HH + (jg >> 2);
            bias[mt][r] = b_ih[col] + b_hh[col];
        }
    const float bo0 = b_out[0], bo1 = b_out[1];

    // readout/embed mapping: row = t>>4 (64 rows), rp = t&15 (16-way partials / 16 embed dims)
    const int rrow = t >> 4;
    const int rp   = t & 15;
    const int grow = row0 + rrow;

    const unsigned short* aHi = Whi + ((size_t)(2 * w) * KT) * 512 + (lane << 3);

    float c8[2][4];
#pragma unroll
    for (int mt = 0; mt < 2; mt++)
#pragma unroll
        for (int nt = 0; nt < 4; nt++) c8[mt][nt] = 0.f;
    float pl0 = 0.f, pl1 = 0.f;                  // p_last (per-row, maintained by all 16 rp-threads)

    __syncthreads();

    // initial embed x[0] from obs delta: thread (rrow, rp=e)
    {
        float d0 = obs[(size_t)1 * BB * 2 + grow * 2 + 0] - obs[(size_t)0 * BB * 2 + grow * 2 + 0];
        float d1 = obs[(size_t)1 * BB * 2 + grow * 2 + 1] - obs[(size_t)0 * BB * 2 + grow * 2 + 1];
        float v = bemb[rp] + d0 * wemb[2 * rp] + d1 * wemb[2 * rp + 1];
        v = v > 0.f ? v : 0.f;
        xhh[rrow * XS + rp] = f2h(v);
    }
    __syncthreads();

#pragma unroll 1
    for (int s = 0; s < NSTEP; s++) {
        // ---- gates GEMM: D[jg][row] = sum_k Wcat[k][jg] * xh[row][k]  (single-term fp16) ----
        f32x4 acc[2][4];
#pragma unroll
        for (int mt = 0; mt < 2; mt++)
#pragma unroll
            for (int nt = 0; nt < 4; nt++) acc[mt][nt] = bias[mt];

#pragma unroll 1
        for (int kt = 0; kt < KT; kt++) {
            const int fo0 = (0 * KT + kt) << 9;
            const int fo1 = (1 * KT + kt) << 9;
            h16x8 ah0 = *(const h16x8*)(aHi + fo0);
            h16x8 ah1 = *(const h16x8*)(aHi + fo1);
            const int koff = (kt << 5) + ((lane >> 4) << 3);
            const unsigned short* bhp = &xhh[(lane & 15) * XS + koff];
#pragma unroll
            for (int nt = 0; nt < 4; nt++) {
                h16x8 bH = *(const h16x8*)(bhp + nt * 16 * XS);
                acc[0][nt] = __builtin_amdgcn_mfma_f32_16x16x32_f16(ah0, bH, acc[0][nt], 0, 0, 0);
                acc[1][nt] = __builtin_amdgcn_mfma_f32_16x16x32_f16(ah1, bH, acc[1][nt], 0, 0, 0);
            }
        }

        // ---- cell update: lane's 4 acc regs = (i,f,g,o) of hidden j -- no shuffles ----
        float hnew[2][4];
#pragma unroll
        for (int mt = 0; mt < 2; mt++)
#pragma unroll
            for (int nt = 0; nt < 4; nt++) {
                f32x4 g = acc[mt][nt];
                float cn = sigm(g[1]) * c8[mt][nt] + sigm(g[0]) * ftanh(g[2]);
                c8[mt][nt] = cn;
                hnew[mt][nt] = sigm(g[3]) * ftanh(cn);
            }

        __syncthreads();   // B_A: all waves finished reading xh for this step

#pragma unroll
        for (int mt = 0; mt < 2; mt++)
#pragma unroll
            for (int nt = 0; nt < 4; nt++) {
                int row = nt * 16 + (lane & 15);
                int j   = 8 * w + mt * 4 + (lane >> 4);
                xhh[row * XS + EE + j] = f2h(hnew[mt][nt]);
            }

        __syncthreads();   // B_B: new h visible to all

        // ---- readout + position + next-step embed ----
        {
            const unsigned short* ph = &xhh[rrow * XS + EE + (rp << 3)];
            s16x8 uh = *(const s16x8*)ph;
            float4 w0a = *(const float4*)&wout[(rp << 3)];
            float4 w0b = *(const float4*)&wout[(rp << 3) + 4];
            float4 w1a = *(const float4*)&wout[HH + (rp << 3)];
            float4 w1b = *(const float4*)&wout[HH + (rp << 3) + 4];
            float hv[8];
#pragma unroll
            for (int q = 0; q < 8; q++)
                hv[q] = h2f((unsigned short)uh[q]);
            float r0 = hv[0]*w0a.x + hv[1]*w0a.y + hv[2]*w0a.z + hv[3]*w0a.w
                     + hv[4]*w0b.x + hv[5]*w0b.y + hv[6]*w0b.z + hv[7]*w0b.w;
            float r1 = hv[0]*w1a.x + hv[1]*w1a.y + hv[2]*w1a.z + hv[3]*w1a.w
                     + hv[4]*w1b.x + hv[5]*w1b.y + hv[6]*w1b.z + hv[7]*w1b.w;
#pragma unroll
            for (int m = 1; m < 16; m <<= 1) {
                r0 += __shfl_xor(r0, m, 64);
                r1 += __shfl_xor(r1, m, 64);
            }
            float base0, base1;
            if (s < OBS) {
                base0 = obs[(size_t)(s + 1) * BB * 2 + grow * 2 + 0];
                base1 = obs[(size_t)(s + 1) * BB * 2 + grow * 2 + 1];
            } else {
                base0 = pl0; base1 = pl1;
            }
            float pos0 = base0 + r0 + bo0;
            float pos1 = base1 + r1 + bo1;
            if (rp == 0) {
                out[((size_t)s * BB + grow) * 2 + 0] = pos0;
                out[((size_t)s * BB + grow) * 2 + 1] = pos1;
            }
            if (s + 1 < NSTEP) {
                float d0, d1;
                if (s + 1 < OBS) {
                    d0 = obs[(size_t)(s + 2) * BB * 2 + grow * 2 + 0] - obs[(size_t)(s + 1) * BB * 2 + grow * 2 + 0];
                    d1 = obs[(size_t)(s + 2) * BB * 2 + grow * 2 + 1] - obs[(size_t)(s + 1) * BB * 2 + grow * 2 + 1];
                } else {
                    d0 = pos0 - pl0;            // p_last_new - p_prev_new
                    d1 = pos1 - pl1;
                }
                float v = bemb[rp] + d0 * wemb[2 * rp] + d1 * wemb[2 * rp + 1];
                v = v > 0.f ? v : 0.f;
                xhh[rrow * XS + rp] = f2h(v);   // x-region write; disjoint from h-reads above
            }
            pl0 = pos0; pl1 = pos1;
        }
        __syncthreads();   // B_C: x[s+1] + p_last consistent before next GEMM
    }
}

extern "C" void kernel_launch(void* const* d_in, const int* in_sizes, int n_in,
                              void* d_out, int out_size, void* d_ws, size_t ws_size,
                              hipStream_t stream)
{
    const float* obs   = (const float*)d_in[0];
    const float* W_emb = (const float*)d_in[1];
    const float* b_emb = (const float*)d_in[2];
    const float* W_ih  = (const float*)d_in[3];
    const float* b_ih  = (const float*)d_in[4];
    const float* W_hh  = (const float*)d_in[5];
    const float* b_hh  = (const float*)d_in[6];
    const float* W_out = (const float*)d_in[7];
    const float* b_out = (const float*)d_in[8];
    float* out = (float*)d_out;

    unsigned short* Whi = (unsigned short*)d_ws;        // 32*5*64*8 = 81920 fp16

    hipLaunchKernelGGL(k_prep, dim3(32 * KT * 64 * 8 / 256), dim3(256), 0, stream,
                       W_ih, W_hh, Whi);

    hipLaunchKernelGGL(k_lstm, dim3(BB / MROWS), dim3(TPB), 0, stream,
                       obs, W_emb, b_emb, b_ih, b_hh, Whi, W_out, b_out, out);
}

// Round 11
// 257.062 us; speedup vs baseline: 1.9107x; 1.0094x over previous
//
#include <hip/hip_runtime.h>
#include <hip/hip_fp16.h>
#include <math.h>

#define BB 32768
#define EE 16
#define HH 128
#define KP 160          // padded K: 16 x + 128 h + 16 zeros
#define XS 168          // xh row stride (f16 elems): 168*2B=336B -> 16B-aligned, 8 bank-start spread
#define OBS 8
#define NSTEP 19
#define TPB 1024
#define MROWS 64        // batch rows per block
#define KT 5            // K-tiles of 32
#define XBUF (MROWS * XS)   // one xh buffer (f16 elems); two buffers double-buffered

typedef short s16x8 __attribute__((ext_vector_type(8)));     // raw 16-bit x8 (LDS storage view)
typedef _Float16 h16x8 __attribute__((ext_vector_type(8)));  // 8 fp16 (4 VGPRs), MFMA A/B frag
typedef float f32x4 __attribute__((ext_vector_type(4)));     // MFMA C/D frag

__device__ __forceinline__ float sigm(float x){ return __builtin_amdgcn_rcpf(1.0f + __expf(-x)); }
__device__ __forceinline__ float ftanh(float x){ float e = __expf(-2.f*x); return (1.f-e)*__builtin_amdgcn_rcpf(1.f+e); }
__device__ __forceinline__ unsigned short f2h(float x){
    __half h = __float2half(x);                 // RNE, single v_cvt_f16_f32
    return __half_as_ushort(h);
}
__device__ __forceinline__ float h2f(unsigned short u){ return __half2float(__ushort_as_half(u)); }

// Pack W_cat = [W_ih | W_hh] (K=144, zero-pad to 160) into MFMA A-operand fragment order,
// single fp16.  Frag (JT 0..31, kt 0..4): lane l, elem j holds
//   W_cat[k = kt*32 + (l>>4)*8 + j][jg = JT*16 + (l&15)],  jg = 4*j_hidden + gate.
__global__ __launch_bounds__(256) void k_prep(
    const float* __restrict__ W_ih, const float* __restrict__ W_hh,
    unsigned short* __restrict__ Whi)
{
    int idx = blockIdx.x * 256 + threadIdx.x;      // exactly 32*5*64*8 = 81920 threads
    int j    = idx & 7;
    int lane = (idx >> 3) & 63;
    int kt   = (idx >> 9) % KT;
    int JT   = idx / (KT * 512);
    int k  = kt * 32 + ((lane >> 4) << 3) + j;
    int jg = JT * 16 + (lane & 15);
    int col = (jg & 3) * HH + (jg >> 2);           // original gate row: g*128 + j_hidden
    float wv = 0.f;
    if (k < EE)            wv = W_ih[col * EE + k];
    else if (k < EE + HH)  wv = W_hh[col * HH + (k - EE)];
    Whi[idx] = f2h(wv);
}

// R10 structure with DOUBLE-BUFFERED xh: GEMM(s) reads buf[s&1]; cell's h(s+1) writes go
// straight to buf[1-(s&1)] with NO barrier (disjoint buffer -- its last readers were
// fenced >=2 barriers ago); B1 = h RAW before readout; embed writes x into buf[1-(s&1)];
// B2 = x RAW before next GEMM.  3 barriers/step -> 2.  Every fp expression byte-identical
// to R10 -> absmax must stay exactly 0.03125.
__global__ __attribute__((amdgpu_flat_work_group_size(TPB, TPB)))
           __attribute__((amdgpu_waves_per_eu(4, 8)))
void k_lstm(
    const float* __restrict__ obs,
    const float* __restrict__ W_emb, const float* __restrict__ b_emb,
    const float* __restrict__ b_ih,  const float* __restrict__ b_hh,
    const unsigned short* __restrict__ Whi,
    const float* __restrict__ W_out, const float* __restrict__ b_out,
    float* __restrict__ out)
{
    __shared__ unsigned short xhh[2 * XBUF];     // fp16 of [x(16)|h(128)|0(16)|pad] x2 buffers
    __shared__ float wout[2 * HH];
    __shared__ float wemb[EE * 2];
    __shared__ float bemb[EE];

    const int t    = threadIdx.x;
    const int lane = t & 63;
    const int w    = t >> 6;                     // wave 0..15: gate-cols jg in [w*32,(w+1)*32)
    const int row0 = blockIdx.x * MROWS;

    if (t < 2 * HH) wout[t] = W_out[t];          // rows 0,1 of W_out (contiguous)
    if (t < EE * 2) wemb[t] = W_emb[t];
    if (t < EE)     bemb[t] = b_emb[t];
    for (int i = t; i < 2 * XBUF; i += TPB) { xhh[i] = 0; }

    // per-lane gate biases: acc[mt] reg r <-> jg = (2w+mt)*16 + (lane>>4)*4 + r
    f32x4 bias[2];
#pragma unroll
    for (int mt = 0; mt < 2; mt++)
#pragma unroll
        for (int r = 0; r < 4; r++) {
            int jg  = (2 * w + mt) * 16 + ((lane >> 4) << 2) + r;
            int col = (jg & 3) * HH + (jg >> 2);
            bias[mt][r] = b_ih[col] + b_hh[col];
        }
    const float bo0 = b_out[0], bo1 = b_out[1];

    // readout/embed mapping: row = t>>4 (64 rows), rp = t&15 (16-way partials / 16 embed dims)
    const int rrow = t >> 4;
    const int rp   = t & 15;
    const int grow = row0 + rrow;

    const unsigned short* aHi = Whi + ((size_t)(2 * w) * KT) * 512 + (lane << 3);

    float c8[2][4];
#pragma unroll
    for (int mt = 0; mt < 2; mt++)
#pragma unroll
        for (int nt = 0; nt < 4; nt++) c8[mt][nt] = 0.f;
    float pl0 = 0.f, pl1 = 0.f;                  // p_last (per-row, maintained by all 16 rp-threads)

    __syncthreads();

    // initial embed x[0] from obs delta into buffer 0: thread (rrow, rp=e)
    {
        float d0 = obs[(size_t)1 * BB * 2 + grow * 2 + 0] - obs[(size_t)0 * BB * 2 + grow * 2 + 0];
        float d1 = obs[(size_t)1 * BB * 2 + grow * 2 + 1] - obs[(size_t)0 * BB * 2 + grow * 2 + 1];
        float v = bemb[rp] + d0 * wemb[2 * rp] + d1 * wemb[2 * rp + 1];
        v = v > 0.f ? v : 0.f;
        xhh[rrow * XS + rp] = f2h(v);
    }
    __syncthreads();

#pragma unroll 1
    for (int s = 0; s < NSTEP; s++) {
        const unsigned short* curb = xhh + ((s & 1) ? XBUF : 0);       // holds x(s)|h(s)
        unsigned short*       nxtb = xhh + ((s & 1) ? 0 : XBUF);       // receives h(s+1), x(s+1)

        // ---- gates GEMM: D[jg][row] = sum_k Wcat[k][jg] * xh[row][k]  (single-term fp16) ----
        f32x4 acc[2][4];
#pragma unroll
        for (int mt = 0; mt < 2; mt++)
#pragma unroll
            for (int nt = 0; nt < 4; nt++) acc[mt][nt] = bias[mt];

#pragma unroll 1
        for (int kt = 0; kt < KT; kt++) {
            const int fo0 = (0 * KT + kt) << 9;
            const int fo1 = (1 * KT + kt) << 9;
            h16x8 ah0 = *(const h16x8*)(aHi + fo0);
            h16x8 ah1 = *(const h16x8*)(aHi + fo1);
            const int koff = (kt << 5) + ((lane >> 4) << 3);
            const unsigned short* bhp = &curb[(lane & 15) * XS + koff];
#pragma unroll
            for (int nt = 0; nt < 4; nt++) {
                h16x8 bH = *(const h16x8*)(bhp + nt * 16 * XS);
                acc[0][nt] = __builtin_amdgcn_mfma_f32_16x16x32_f16(ah0, bH, acc[0][nt], 0, 0, 0);
                acc[1][nt] = __builtin_amdgcn_mfma_f32_16x16x32_f16(ah1, bH, acc[1][nt], 0, 0, 0);
            }
        }

        // ---- cell update + h-write straight to the OTHER buffer (no barrier needed) ----
#pragma unroll
        for (int mt = 0; mt < 2; mt++)
#pragma unroll
            for (int nt = 0; nt < 4; nt++) {
                f32x4 g = acc[mt][nt];
                float cn = sigm(g[1]) * c8[mt][nt] + sigm(g[0]) * ftanh(g[2]);
                c8[mt][nt] = cn;
                float hn = sigm(g[3]) * ftanh(cn);
                int row = nt * 16 + (lane & 15);
                int j   = 8 * w + mt * 4 + (lane >> 4);
                nxtb[row * XS + EE + j] = f2h(hn);
            }

        __syncthreads();   // B1: h(s+1) visible in nxtb

        // ---- readout + position + next-step embed (reads nxtb h; embed writes nxtb x) ----
        {
            const unsigned short* ph = &nxtb[rrow * XS + EE + (rp << 3)];
            s16x8 uh = *(const s16x8*)ph;
            float4 w0a = *(const float4*)&wout[(rp << 3)];
            float4 w0b = *(const float4*)&wout[(rp << 3) + 4];
            float4 w1a = *(const float4*)&wout[HH + (rp << 3)];
            float4 w1b = *(const float4*)&wout[HH + (rp << 3) + 4];
            float hv[8];
#pragma unroll
            for (int q = 0; q < 8; q++)
                hv[q] = h2f((unsigned short)uh[q]);
            float r0 = hv[0]*w0a.x + hv[1]*w0a.y + hv[2]*w0a.z + hv[3]*w0a.w
                     + hv[4]*w0b.x + hv[5]*w0b.y + hv[6]*w0b.z + hv[7]*w0b.w;
            float r1 = hv[0]*w1a.x + hv[1]*w1a.y + hv[2]*w1a.z + hv[3]*w1a.w
                     + hv[4]*w1b.x + hv[5]*w1b.y + hv[6]*w1b.z + hv[7]*w1b.w;
#pragma unroll
            for (int m = 1; m < 16; m <<= 1) {
                r0 += __shfl_xor(r0, m, 64);
                r1 += __shfl_xor(r1, m, 64);
            }
            float base0, base1;
            if (s < OBS) {
                base0 = obs[(size_t)(s + 1) * BB * 2 + grow * 2 + 0];
                base1 = obs[(size_t)(s + 1) * BB * 2 + grow * 2 + 1];
            } else {
                base0 = pl0; base1 = pl1;
            }
            float pos0 = base0 + r0 + bo0;
            float pos1 = base1 + r1 + bo1;
            if (rp == 0) {
                out[((size_t)s * BB + grow) * 2 + 0] = pos0;
                out[((size_t)s * BB + grow) * 2 + 1] = pos1;
            }
            if (s + 1 < NSTEP) {
                float d0, d1;
                if (s + 1 < OBS) {
                    d0 = obs[(size_t)(s + 2) * BB * 2 + grow * 2 + 0] - obs[(size_t)(s + 1) * BB * 2 + grow * 2 + 0];
                    d1 = obs[(size_t)(s + 2) * BB * 2 + grow * 2 + 1] - obs[(size_t)(s + 1) * BB * 2 + grow * 2 + 1];
                } else {
                    d0 = pos0 - pl0;            // p_last_new - p_prev_new
                    d1 = pos1 - pl1;
                }
                float v = bemb[rp] + d0 * wemb[2 * rp] + d1 * wemb[2 * rp + 1];
                v = v > 0.f ? v : 0.f;
                nxtb[rrow * XS + rp] = f2h(v);  // x-region write; disjoint from h-reads above
            }
            pl0 = pos0; pl1 = pos1;
        }
        __syncthreads();   // B2: x(s+1)+h(s+1) consistent in nxtb before next GEMM
    }
}

extern "C" void kernel_launch(void* const* d_in, const int* in_sizes, int n_in,
                              void* d_out, int out_size, void* d_ws, size_t ws_size,
                              hipStream_t stream)
{
    const float* obs   = (const float*)d_in[0];
    const float* W_emb = (const float*)d_in[1];
    const float* b_emb = (const float*)d_in[2];
    const float* W_ih  = (const float*)d_in[3];
    const float* b_ih  = (const float*)d_in[4];
    const float* W_hh  = (const float*)d_in[5];
    const float* b_hh  = (const float*)d_in[6];
    const float* W_out = (const float*)d_in[7];
    const float* b_out = (const float*)d_in[8];
    float* out = (float*)d_out;

    unsigned short* Whi = (unsigned short*)d_ws;        // 32*5*64*8 = 81920 fp16

    hipLaunchKernelGGL(k_prep, dim3(32 * KT * 64 * 8 / 256), dim3(256), 0, stream,
                       W_ih, W_hh, Whi);

    hipLaunchKernelGGL(k_lstm, dim3(BB / MROWS), dim3(TPB), 0, stream,
                       obs, W_emb, b_emb, b_ih, b_hh, Whi, W_out, b_out, out);
}

// Round 12
// 238.127 us; speedup vs baseline: 2.0626x; 1.0795x over previous
//
#include <hip/hip_runtime.h>
#include <hip/hip_fp16.h>
#include <math.h>

#define BB 32768
#define EE 16
#define HH 128
#define KP 160          // padded K: 16 x + 128 h + 16 zeros
#define XS 168          // xh row stride (f16 elems): 168*2B=336B -> 16B-aligned, 8 bank-start spread
#define OBS 8
#define NSTEP 19
#define TPB 1024
#define MROWS 64        // batch rows per block
#define KT 5            // K-tiles of 32
#define XBUF (MROWS * XS)   // one xh buffer (f16 elems); two buffers double-buffered

typedef short s16x8 __attribute__((ext_vector_type(8)));     // raw 16-bit x8 (LDS storage view)
typedef _Float16 h16x8 __attribute__((ext_vector_type(8)));  // 8 fp16 (4 VGPRs), MFMA A/B frag
typedef float f32x4 __attribute__((ext_vector_type(4)));     // MFMA C/D frag

__device__ __forceinline__ float sigm(float x){ return __builtin_amdgcn_rcpf(1.0f + __expf(-x)); }
__device__ __forceinline__ float ftanh(float x){ float e = __expf(-2.f*x); return (1.f-e)*__builtin_amdgcn_rcpf(1.f+e); }
__device__ __forceinline__ unsigned short f2h(float x){
    __half h = __float2half(x);                 // RNE, single v_cvt_f16_f32
    return __half_as_ushort(h);
}
__device__ __forceinline__ float h2f(unsigned short u){ return __half2float(__ushort_as_half(u)); }

// Pack W_cat = [W_ih | W_hh] (K=144, zero-pad to 160) into MFMA A-operand fragment order,
// single fp16.  Frag (JT 0..31, kt 0..4): lane l, elem j holds
//   W_cat[k = kt*32 + (l>>4)*8 + j][jg = JT*16 + (l&15)],  jg = 4*j_hidden + gate.
__global__ __launch_bounds__(256) void k_prep(
    const float* __restrict__ W_ih, const float* __restrict__ W_hh,
    unsigned short* __restrict__ Whi)
{
    int idx = blockIdx.x * 256 + threadIdx.x;      // exactly 32*5*64*8 = 81920 threads
    int j    = idx & 7;
    int lane = (idx >> 3) & 63;
    int kt   = (idx >> 9) % KT;
    int JT   = idx / (KT * 512);
    int k  = kt * 32 + ((lane >> 4) << 3) + j;
    int jg = JT * 16 + (lane & 15);
    int col = (jg & 3) * HH + (jg >> 2);           // original gate row: g*128 + j_hidden
    float wv = 0.f;
    if (k < EE)            wv = W_ih[col * EE + k];
    else if (k < EE + HH)  wv = W_hh[col * HH + (k - EE)];
    Whi[idx] = f2h(wv);
}

// R11 structure (double-buffered xh, 2 barriers/step) + A-fragments hoisted to registers
// (loop-invariant across all 19 steps: 2x5x8 fp16 = 40 VGPR, ~100 live < 128 budget) and
// fully-unrolled GEMM: 20 ds_read_b128 off one base pointer with compile-time immediate
// offsets (max 16KB < 64KB range) -- zero per-step global loads / address VALU in the
// GEMM.  MFMA per-acc order, cell, readout all byte-identical to R11 -> absmax must stay
// exactly 0.03125.
__global__ __attribute__((amdgpu_flat_work_group_size(TPB, TPB)))
           __attribute__((amdgpu_waves_per_eu(4, 8)))
void k_lstm(
    const float* __restrict__ obs,
    const float* __restrict__ W_emb, const float* __restrict__ b_emb,
    const float* __restrict__ b_ih,  const float* __restrict__ b_hh,
    const unsigned short* __restrict__ Whi,
    const float* __restrict__ W_out, const float* __restrict__ b_out,
    float* __restrict__ out)
{
    __shared__ unsigned short xhh[2 * XBUF];     // fp16 of [x(16)|h(128)|0(16)|pad] x2 buffers
    __shared__ float wout[2 * HH];
    __shared__ float wemb[EE * 2];
    __shared__ float bemb[EE];

    const int t    = threadIdx.x;
    const int lane = t & 63;
    const int w    = t >> 6;                     // wave 0..15: gate-cols jg in [w*32,(w+1)*32)
    const int row0 = blockIdx.x * MROWS;

    if (t < 2 * HH) wout[t] = W_out[t];          // rows 0,1 of W_out (contiguous)
    if (t < EE * 2) wemb[t] = W_emb[t];
    if (t < EE)     bemb[t] = b_emb[t];
    for (int i = t; i < 2 * XBUF; i += TPB) { xhh[i] = 0; }

    // per-lane gate biases: acc[mt] reg r <-> jg = (2w+mt)*16 + (lane>>4)*4 + r
    f32x4 bias[2];
#pragma unroll
    for (int mt = 0; mt < 2; mt++)
#pragma unroll
        for (int r = 0; r < 4; r++) {
            int jg  = (2 * w + mt) * 16 + ((lane >> 4) << 2) + r;
            int col = (jg & 3) * HH + (jg >> 2);
            bias[mt][r] = b_ih[col] + b_hh[col];
        }
    const float bo0 = b_out[0], bo1 = b_out[1];

    // A-fragments: loop-invariant across all steps -> load ONCE into registers (40 VGPR)
    const unsigned short* aHi = Whi + ((size_t)(2 * w) * KT) * 512 + (lane << 3);
    h16x8 aF[2][KT];
#pragma unroll
    for (int mt = 0; mt < 2; mt++)
#pragma unroll
        for (int kt = 0; kt < KT; kt++)
            aF[mt][kt] = *(const h16x8*)(aHi + ((mt * KT + kt) << 9));

    // readout/embed mapping: row = t>>4 (64 rows), rp = t&15 (16-way partials / 16 embed dims)
    const int rrow = t >> 4;
    const int rp   = t & 15;
    const int grow = row0 + rrow;

    // per-buffer base pointers (lane-derived, step-invariant)
    const int bofs = (lane & 15) * XS + ((lane >> 4) << 3);     // GEMM B-frag base (elems)
    const unsigned short* bp0 = xhh + bofs;
    const unsigned short* bp1 = xhh + XBUF + bofs;

    float c8[2][4];
#pragma unroll
    for (int mt = 0; mt < 2; mt++)
#pragma unroll
        for (int nt = 0; nt < 4; nt++) c8[mt][nt] = 0.f;
    float pl0 = 0.f, pl1 = 0.f;                  // p_last (per-row, maintained by all 16 rp-threads)

    __syncthreads();

    // initial embed x[0] from obs delta into buffer 0: thread (rrow, rp=e)
    {
        float d0 = obs[(size_t)1 * BB * 2 + grow * 2 + 0] - obs[(size_t)0 * BB * 2 + grow * 2 + 0];
        float d1 = obs[(size_t)1 * BB * 2 + grow * 2 + 1] - obs[(size_t)0 * BB * 2 + grow * 2 + 1];
        float v = bemb[rp] + d0 * wemb[2 * rp] + d1 * wemb[2 * rp + 1];
        v = v > 0.f ? v : 0.f;
        xhh[rrow * XS + rp] = f2h(v);
    }
    __syncthreads();

#pragma unroll 1
    for (int s = 0; s < NSTEP; s++) {
        const unsigned short* bhp  = (s & 1) ? bp1 : bp0;              // reads x(s)|h(s)
        unsigned short*       nxtb = xhh + ((s & 1) ? 0 : XBUF);       // receives h(s+1), x(s+1)

        // ---- gates GEMM: fully unrolled, immediate-offset ds_reads, register A ----
        f32x4 acc[2][4];
#pragma unroll
        for (int mt = 0; mt < 2; mt++)
#pragma unroll
            for (int nt = 0; nt < 4; nt++) acc[mt][nt] = bias[mt];

#pragma unroll
        for (int kt = 0; kt < KT; kt++) {
#pragma unroll
            for (int nt = 0; nt < 4; nt++) {
                h16x8 bH = *(const h16x8*)(bhp + kt * 32 + nt * 16 * XS);
                acc[0][nt] = __builtin_amdgcn_mfma_f32_16x16x32_f16(aF[0][kt], bH, acc[0][nt], 0, 0, 0);
                acc[1][nt] = __builtin_amdgcn_mfma_f32_16x16x32_f16(aF[1][kt], bH, acc[1][nt], 0, 0, 0);
            }
        }

        // ---- cell update + h-write straight to the OTHER buffer (no barrier needed) ----
#pragma unroll
        for (int mt = 0; mt < 2; mt++)
#pragma unroll
            for (int nt = 0; nt < 4; nt++) {
                f32x4 g = acc[mt][nt];
                float cn = sigm(g[1]) * c8[mt][nt] + sigm(g[0]) * ftanh(g[2]);
                c8[mt][nt] = cn;
                float hn = sigm(g[3]) * ftanh(cn);
                int row = nt * 16 + (lane & 15);
                int j   = 8 * w + mt * 4 + (lane >> 4);
                nxtb[row * XS + EE + j] = f2h(hn);
            }

        __syncthreads();   // B1: h(s+1) visible in nxtb

        // ---- readout + position + next-step embed (reads nxtb h; embed writes nxtb x) ----
        {
            const unsigned short* ph = &nxtb[rrow * XS + EE + (rp << 3)];
            s16x8 uh = *(const s16x8*)ph;
            float4 w0a = *(const float4*)&wout[(rp << 3)];
            float4 w0b = *(const float4*)&wout[(rp << 3) + 4];
            float4 w1a = *(const float4*)&wout[HH + (rp << 3)];
            float4 w1b = *(const float4*)&wout[HH + (rp << 3) + 4];
            float hv[8];
#pragma unroll
            for (int q = 0; q < 8; q++)
                hv[q] = h2f((unsigned short)uh[q]);
            float r0 = hv[0]*w0a.x + hv[1]*w0a.y + hv[2]*w0a.z + hv[3]*w0a.w
                     + hv[4]*w0b.x + hv[5]*w0b.y + hv[6]*w0b.z + hv[7]*w0b.w;
            float r1 = hv[0]*w1a.x + hv[1]*w1a.y + hv[2]*w1a.z + hv[3]*w1a.w
                     + hv[4]*w1b.x + hv[5]*w1b.y + hv[6]*w1b.z + hv[7]*w1b.w;
#pragma unroll
            for (int m = 1; m < 16; m <<= 1) {
                r0 += __shfl_xor(r0, m, 64);
                r1 += __shfl_xor(r1, m, 64);
            }
            float base0, base1;
            if (s < OBS) {
                base0 = obs[(size_t)(s + 1) * BB * 2 + grow * 2 + 0];
                base1 = obs[(size_t)(s + 1) * BB * 2 + grow * 2 + 1];
            } else {
                base0 = pl0; base1 = pl1;
            }
            float pos0 = base0 + r0 + bo0;
            float pos1 = base1 + r1 + bo1;
            if (rp == 0) {
                out[((size_t)s * BB + grow) * 2 + 0] = pos0;
                out[((size_t)s * BB + grow) * 2 + 1] = pos1;
            }
            if (s + 1 < NSTEP) {
                float d0, d1;
                if (s + 1 < OBS) {
                    d0 = obs[(size_t)(s + 2) * BB * 2 + grow * 2 + 0] - obs[(size_t)(s + 1) * BB * 2 + grow * 2 + 0];
                    d1 = obs[(size_t)(s + 2) * BB * 2 + grow * 2 + 1] - obs[(size_t)(s + 1) * BB * 2 + grow * 2 + 1];
                } else {
                    d0 = pos0 - pl0;            // p_last_new - p_prev_new
                    d1 = pos1 - pl1;
                }
                float v = bemb[rp] + d0 * wemb[2 * rp] + d1 * wemb[2 * rp + 1];
                v = v > 0.f ? v : 0.f;
                nxtb[rrow * XS + rp] = f2h(v);  // x-region write; disjoint from h-reads above
            }
            pl0 = pos0; pl1 = pos1;
        }
        __syncthreads();   // B2: x(s+1)+h(s+1) consistent in nxtb before next GEMM
    }
}

extern "C" void kernel_launch(void* const* d_in, const int* in_sizes, int n_in,
                              void* d_out, int out_size, void* d_ws, size_t ws_size,
                              hipStream_t stream)
{
    const float* obs   = (const float*)d_in[0];
    const float* W_emb = (const float*)d_in[1];
    const float* b_emb = (const float*)d_in[2];
    const float* W_ih  = (const float*)d_in[3];
    const float* b_ih  = (const float*)d_in[4];
    const float* W_hh  = (const float*)d_in[5];
    const float* b_hh  = (const float*)d_in[6];
    const float* W_out = (const float*)d_in[7];
    const float* b_out = (const float*)d_in[8];
    float* out = (float*)d_out;

    unsigned short* Whi = (unsigned short*)d_ws;        // 32*5*64*8 = 81920 fp16

    hipLaunchKernelGGL(k_prep, dim3(32 * KT * 64 * 8 / 256), dim3(256), 0, stream,
                       W_ih, W_hh, Whi);

    hipLaunchKernelGGL(k_lstm, dim3(BB / MROWS), dim3(TPB), 0, stream,
                       obs, W_emb, b_emb, b_ih, b_hh, Whi, W_out, b_out, out);
}